// Round 19
// baseline (164.641 us; speedup 1.0000x reference)
//
#include <hip/hip_runtime.h>

typedef __bf16 bf16;
typedef __bf16 bf16x8 __attribute__((ext_vector_type(8)));
typedef __bf16 bf16x4 __attribute__((ext_vector_type(4)));
typedef float f32x4 __attribute__((ext_vector_type(4)));
typedef float f32x16 __attribute__((ext_vector_type(16)));
typedef unsigned int u32;
typedef unsigned int u32x2 __attribute__((ext_vector_type(2)));
typedef unsigned int u32x4 __attribute__((ext_vector_type(4)));

#define MFMA16(a, b, c) __builtin_amdgcn_mfma_f32_16x16x32_bf16(a, b, c, 0, 0, 0)
#define MFMA32(a, b, c) __builtin_amdgcn_mfma_f32_32x32x16_bf16(a, b, c, 0, 0, 0)

__device__ __forceinline__ u32 pack2(float a, float b) {
  unsigned short ua = __builtin_bit_cast(unsigned short, (bf16)a);
  unsigned short ub = __builtin_bit_cast(unsigned short, (bf16)b);
  return (u32)ua | ((u32)ub << 16);
}

__device__ __forceinline__ void lnrelu16(const float* in, float* out,
                                         const float* __restrict__ g,
                                         const float* __restrict__ b) {
  float mu = 0.f;
#pragma unroll
  for (int t = 0; t < 16; ++t) mu += in[t];
  mu *= 0.0625f;
  float var = 0.f;
#pragma unroll
  for (int t = 0; t < 16; ++t) { float d = in[t] - mu; var += d * d; }
  var *= 0.0625f;
  float inv = rsqrtf(var + 1e-5f);
#pragma unroll
  for (int t = 0; t < 16; ++t) {
    float v = (in[t] - mu) * inv * g[t] + b[t];
    out[t] = fmaxf(v, 0.f);
  }
}

// ---------------- merged prep: wpack (blk 0-95) | proj cvt (96-159) | dpb (160-163) ----------------
__global__ __launch_bounds__(256) void k_prep(
    const float* __restrict__ qkvw, bf16* __restrict__ wqkv,
    const float* __restrict__ pjw, bf16* __restrict__ wpj,
    const float* __restrict__ ppw, const float* __restrict__ ppb,
    const float* __restrict__ g1, const float* __restrict__ b1,
    const float* __restrict__ f1w, const float* __restrict__ f1b,
    const float* __restrict__ g2, const float* __restrict__ b2,
    const float* __restrict__ f2w, const float* __restrict__ f2b,
    const float* __restrict__ g3, const float* __restrict__ b3,
    const float* __restrict__ f3w, const float* __restrict__ f3b,
    float* __restrict__ ptab) {
  const int blk = blockIdx.x;
  if (blk < 96) {
    // qkv_w -> B-fragment-major pack: Wf[(ot*8+kc)*64+lane][8]
    int t = blk * 256 + threadIdx.x;
    int lane = t & 63, fk = t >> 6;
    int ot = fk >> 3, kc = fk & 7;
    int o = ot * 16 + (lane & 15), cb = kc * 32 + (lane >> 4) * 8;
    const float* src = qkvw + o * 256 + cb;
    bf16x8 v;
#pragma unroll
    for (int j = 0; j < 8; ++j) v[j] = (bf16)src[j];
    *(bf16x8*)(wqkv + (size_t)t * 8) = v;
  } else if (blk < 160) {
    // proj_w fp32 -> bf16
    int i = (blk - 96) * 256 + threadIdx.x;
    if (i < 16384) {
      float4 v = ((const float4*)pjw)[i];
      bf16x4 o;
      o[0] = (bf16)v.x; o[1] = (bf16)v.y; o[2] = (bf16)v.z; o[3] = (bf16)v.w;
      ((bf16x4*)wpj)[i] = o;
    }
  } else {
    // dynamic position-bias MLP (961 rows)
    int l = (blk - 160) * 256 + threadIdx.x;
    if (l >= 961) return;
    float dh = (float)(l / 31) - 15.f;
    float dw = (float)(l % 31) - 15.f;
    float p[16], a[16], y[16];
#pragma unroll
    for (int t = 0; t < 16; ++t)
      p[t] = dh * ppw[2 * t] + dw * ppw[2 * t + 1] + ppb[t];
    lnrelu16(p, a, g1, b1);
#pragma unroll
    for (int t = 0; t < 16; ++t) {
      float s = f1b[t];
#pragma unroll
      for (int u = 0; u < 16; ++u) s += a[u] * f1w[t * 16 + u];
      y[t] = s;
    }
    lnrelu16(y, a, g2, b2);
#pragma unroll
    for (int t = 0; t < 16; ++t) {
      float s = f2b[t];
#pragma unroll
      for (int u = 0; u < 16; ++u) s += a[u] * f2w[t * 16 + u];
      p[t] = s;
    }
    lnrelu16(p, a, g3, b3);
#pragma unroll
    for (int t = 0; t < 8; ++t) {
      float s = f3b[t];
#pragma unroll
      for (int u = 0; u < 16; ++u) s += a[u] * f3w[t * 16 + u];
      ptab[l * 8 + t] = s;
    }
  }
}

// ---------------- bias table (bf16) in 32x32 MFMA D-fragment order ----------------
__global__ __launch_bounds__(256) void k_bias(const float* __restrict__ ptab,
                                              bf16* __restrict__ Bsw) {
  int idx = blockIdx.x * 256 + threadIdx.x;  // 128 blocks -> 32768 threads
  int lane = idx & 63, tg = idx >> 6;        // tg 0..511
  int h = tg >> 6, qt = (tg >> 3) & 7, kt2 = tg & 7;
  int l31 = lane & 31, hi2 = lane >> 5;
  int n = qt * 32 + l31;
  int i1 = n >> 4, j1 = n & 15;
  bf16x8 o0, o1;
#pragma unroll
  for (int reg = 0; reg < 16; ++reg) {
    int key = kt2 * 32 + (reg & 3) + 8 * (reg >> 2) + 4 * hi2;
    int i2 = key >> 4, j2 = key & 15;
    int li = (i1 - i2 + 15) * 31 + (j1 - j2 + 15);
    bf16 v = (bf16)ptab[li * 8 + h];
    if (reg < 8) o0[reg] = v; else o1[reg - 8] = v;
  }
  bf16* dst = Bsw + tg * 1024 + lane * 16;
  *(bf16x8*)dst = o0;
  *(bf16x8*)(dst + 8) = o1;
}

// ---------------- qkv GEMM: (B*N,256) x (768,256)^T ----------------
// R17 geometry (512 threads, grid 512, 128-row Xl, dbuf kc loop) with q/k
// epilogue routed through the per-wave LDS bounce: 16B coalesced global
// stores (24/thread) replace 192 scalar 2B stores (vmcnt pressure fix).
__global__ __launch_bounds__(512) void k_qkv(
    const float* __restrict__ x, const bf16* __restrict__ Wf,
    const float* __restrict__ qb, bf16* __restrict__ q, bf16* __restrict__ kk,
    bf16* __restrict__ vT) {
  __shared__ bf16 Xl[128 * 256];   // 65,536 B, swizzled [n][c]
  __shared__ bf16 Vb[8][16 * 36];  // 9,216 B: per-wave bounce (v AND q/k)
  const int b = blockIdx.x >> 1;
  const int nh = blockIdx.x & 1;
  const int tid = threadIdx.x;
  const int lane = tid & 63;
  const int wave = tid >> 6;
  const int wm = wave & 1, wo = wave >> 1;
  const int l15 = lane & 15, l4 = lane >> 4;
  const int n0w = nh * 128 + wm * 64;

  // ---- stage x[b][c][nh*128+n] -> Xl[n][c] via quad transpose + swizzle ----
  {
    const float* xb = x + b * 65536 + nh * 128;
    const int p = tid & 3;
    const int Q = tid >> 2;
    const int n0 = (Q & 31) * 4;
    const int cgb = Q >> 5;  // 0..3
#pragma unroll
    for (int it = 0; it < 16; ++it) {
      const int c0 = (cgb + it * 4) * 4;
      float4 v = *(const float4*)(xb + (c0 + p) * 256 + n0);
      u32 u0 = pack2(v.x, v.y);
      u32 u1 = pack2(v.z, v.w);
      u32 su0 = __shfl_xor(u0, 1);
      u32 su1 = __shfl_xor(u1, 1);
      u32 w, z;
      if (p & 1) {
        w = (su0 >> 16) | (u0 & 0xffff0000u);
        z = (su1 >> 16) | (u1 & 0xffff0000u);
      } else {
        w = (u0 & 0xffffu) | (su0 << 16);
        z = (u1 & 0xffffu) | (su1 << 16);
      }
      u32 sw = __shfl_xor(w, 2);
      u32 sz = __shfl_xor(z, 2);
      u32x2 o2;
      o2[0] = (p & 2) ? sz : w;
      o2[1] = (p & 2) ? z : sw;
      const int n = n0 + p;
      const int wb = (2 * c0) ^ ((n & 7) << 4);
      *(u32x2*)((char*)Xl + n * 512 + wb) = o2;
    }
  }
  __syncthreads();

  const f32x4 fz = {0.f, 0.f, 0.f, 0.f};
  bf16* lb = Vb[wave];
  for (int og = 0; og < 3; ++og) {
    const int ot0 = wo * 12 + og * 4;
    f32x4 acc[4][4];  // [nt][oi]
#pragma unroll
    for (int nt = 0; nt < 4; ++nt)
#pragma unroll
      for (int oi = 0; oi < 4; ++oi) acc[nt][oi] = fz;

    bf16x8 afr[2][4], bfr[2][4];
#pragma unroll
    for (int nt = 0; nt < 4; ++nt) {
      int nn = wm * 64 + nt * 16 + l15;
      int wb = (l4 * 16) ^ ((nn & 7) << 4);
      afr[0][nt] = *(const bf16x8*)((const char*)Xl + nn * 512 + wb);
    }
#pragma unroll
    for (int oi = 0; oi < 4; ++oi)
      bfr[0][oi] = *(const bf16x8*)(Wf + (((ot0 + oi) * 8) * 64 + lane) * 8);

#pragma unroll
    for (int kc = 0; kc < 8; ++kc) {
      const int cur = kc & 1, nxt = cur ^ 1;
      if (kc < 7) {
#pragma unroll
        for (int nt = 0; nt < 4; ++nt) {
          int nn = wm * 64 + nt * 16 + l15;
          int wb = ((kc + 1) * 64 + l4 * 16) ^ ((nn & 7) << 4);
          afr[nxt][nt] = *(const bf16x8*)((const char*)Xl + nn * 512 + wb);
        }
#pragma unroll
        for (int oi = 0; oi < 4; ++oi)
          bfr[nxt][oi] =
              *(const bf16x8*)(Wf + ((((ot0 + oi) * 8) + kc + 1) * 64 + lane) * 8);
      }
#pragma unroll
      for (int nt = 0; nt < 4; ++nt)
#pragma unroll
        for (int oi = 0; oi < 4; ++oi)
          acc[nt][oi] = MFMA16(afr[cur][nt], bfr[cur][oi], acc[nt][oi]);
    }

    // ---- epilogue; each (wo,og) group lies entirely in one segment ----
    const int seg = ot0 >> 4;  // 0=q 1=k 2=v
    if (seg < 2) {
      bf16* dstbuf = (seg == 0) ? q : kk;
      const float scale = (seg == 0) ? 0.17677669529663687f : 1.0f;
#pragma unroll
      for (int p = 0; p < 2; ++p) {  // head-pair: oi (2p, 2p+1) = full 32 d
        int ot = ot0 + 2 * p;
        int h = (ot >> 1) & 7;
        int base = (b * 8 + h) * 8192;
        float bias0 = qb[seg * 256 + h * 32 + l15];
        float bias1 = qb[seg * 256 + h * 32 + 16 + l15];
#pragma unroll
        for (int nt = 0; nt < 4; ++nt) {
          // 16 rows x 32 d tile into [16][36] bounce (2-way-free banks)
#pragma unroll
          for (int r = 0; r < 4; ++r) {
            int row = l4 * 4 + r;
            lb[row * 36 + l15] = (bf16)((acc[nt][2 * p][r] + bias0) * scale);
            lb[row * 36 + 16 + l15] =
                (bf16)((acc[nt][2 * p + 1][r] + bias1) * scale);
          }
          asm volatile("s_waitcnt lgkmcnt(0)" ::: "memory");
          __builtin_amdgcn_sched_barrier(0);
          int row = lane >> 2, ch = lane & 3;
          bf16x8 tv = *(const bf16x8*)(lb + row * 36 + ch * 8);
          asm volatile("s_waitcnt lgkmcnt(0)" ::: "memory");
          __builtin_amdgcn_sched_barrier(0);
          // 64 lanes x 16B = 1KB contiguous ([n][32] rows are contiguous)
          *(bf16x8*)(dstbuf + base + (n0w + nt * 16 + row) * 32 + ch * 8) = tv;
        }
      }
    } else {
      // v: transpose 16d x 32n tiles through LDS -> vT[d][n] 64B rows
#pragma unroll
      for (int oi = 0; oi < 4; ++oi) {
        int ot = ot0 + oi;
        int o = ot * 16 + l15;
        float bias = qb[o];
        int h = (o >> 5) & 7;
        int d = o & 31;
        int base = (b * 8 + h) * 8192;
#pragma unroll
        for (int pr = 0; pr < 2; ++pr) {
          f32x4 acc0 = acc[2 * pr][oi], acc1 = acc[2 * pr + 1][oi];
          int n0p = n0w + pr * 32;
#pragma unroll
          for (int nt = 0; nt < 2; ++nt) {
            f32x4 a = nt ? acc1 : acc0;
            *(u32*)(lb + l15 * 36 + nt * 16 + l4 * 4) =
                pack2(a[0] + bias, a[1] + bias);
            *(u32*)(lb + l15 * 36 + nt * 16 + l4 * 4 + 2) =
                pack2(a[2] + bias, a[3] + bias);
          }
          asm volatile("s_waitcnt lgkmcnt(0)" ::: "memory");
          __builtin_amdgcn_sched_barrier(0);
          int dl = lane >> 2, chv = lane & 3;
          bf16x4 rv0 = *(bf16x4*)(lb + dl * 36 + chv * 8);
          bf16x4 rv1 = *(bf16x4*)(lb + dl * 36 + chv * 8 + 4);
          asm volatile("s_waitcnt lgkmcnt(0)" ::: "memory");
          __builtin_amdgcn_sched_barrier(0);
          int d2 = (ot & 1) * 16 + dl;
          bf16* dv2 = vT + base + d2 * 256 + n0p + chv * 8;
          *(bf16x4*)dv2 = rv0;
          *(bf16x4*)(dv2 + 4) = rv1;
        }
      }
    }
  }
}

// ---------------- attention per (b, h): fused QK->exp->PV per kt2 ----------------
__global__ __launch_bounds__(256, 4) void k_attn(
    const bf16* __restrict__ q, const bf16* __restrict__ kk,
    const bf16* __restrict__ vT, const bf16* __restrict__ Bsw,
    bf16* __restrict__ ao) {
  __shared__ bf16 Kl[256 * 36];    // 18,432 B
  __shared__ bf16 Ob[4][32 * 36];  // 9,216 B: per-wave output transpose bounce
  const int bh = blockIdx.x;
  const int b = bh >> 3, h = bh & 7;
  const int tid = threadIdx.x;
  const int lane = tid & 63, wave = tid >> 6;
  const int l31 = lane & 31, hi = lane >> 5;

  const bf16* Kg = kk + bh * 8192;
#pragma unroll
  for (int i = 0; i < 4; ++i) {
    int t = tid + i * 256;
    int n = t >> 2, dc = t & 3;
    *(bf16x8*)(Kl + n * 36 + dc * 8) = *(const bf16x8*)(Kg + n * 32 + dc * 8);
  }
  __syncthreads();

  const bf16* Vg = vT + bh * 8192;
  bf16* ob = Ob[wave];
  for (int qi = 0; qi < 2; ++qi) {
    const int qt = wave * 2 + qi, q0 = qt * 32;
    bf16x8 qf0 = *(const bf16x8*)(q + bh * 8192 + (q0 + l31) * 32 + hi * 8);
    bf16x8 qf1 = *(const bf16x8*)(q + bh * 8192 + (q0 + l31) * 32 + 16 + hi * 8);
    const bf16* bq = Bsw + (h * 8 + qt) * 8192 + lane * 16;
    float lsum = 0.f;
    f32x16 o;
#pragma unroll
    for (int i = 0; i < 16; ++i) o[i] = 0.f;
#pragma unroll
    for (int kt2 = 0; kt2 < 8; ++kt2) {
      u32x4 w0 = *(const u32x4*)(bq + kt2 * 1024);       // bias regs 0..7
      u32x4 w1 = *(const u32x4*)(bq + kt2 * 1024 + 8);   // bias regs 8..15
      f32x16 acc;
#pragma unroll
      for (int j = 0; j < 4; ++j) {
        acc[2 * j] = __builtin_bit_cast(float, w0[j] << 16);
        acc[2 * j + 1] = __builtin_bit_cast(float, w0[j] & 0xffff0000u);
        acc[8 + 2 * j] = __builtin_bit_cast(float, w1[j] << 16);
        acc[8 + 2 * j + 1] = __builtin_bit_cast(float, w1[j] & 0xffff0000u);
      }
      bf16x8 kf0 = *(const bf16x8*)(Kl + (kt2 * 32 + l31) * 36 + hi * 8);
      bf16x8 kf1 = *(const bf16x8*)(Kl + (kt2 * 32 + l31) * 36 + 16 + hi * 8);
      acc = MFMA32(kf0, qf0, acc);
      acc = MFMA32(kf1, qf1, acc);
      // exp (no max-shift) + pack; P for this kt2 feeds PV immediately
      u32 lo[4], hw[4];
#pragma unroll
      for (int qq = 0; qq < 4; ++qq) {
        float e0 = __expf(acc[4 * qq]);
        float e1 = __expf(acc[4 * qq + 1]);
        float e2 = __expf(acc[4 * qq + 2]);
        float e3 = __expf(acc[4 * qq + 3]);
        lsum += (e0 + e1) + (e2 + e3);
        lo[qq] = pack2(e0, e1);
        hw[qq] = pack2(e2, e3);
      }
#pragma unroll
      for (int sb = 0; sb < 2; ++sb) {
        u32 keep_lo = hi ? lo[2 * sb + 1] : lo[2 * sb];
        u32 keep_hi = hi ? hw[2 * sb + 1] : hw[2 * sb];
        u32 send_lo = hi ? lo[2 * sb] : lo[2 * sb + 1];
        u32 send_hi = hi ? hw[2 * sb] : hw[2 * sb + 1];
        u32 rlo = __shfl_xor(send_lo, 32);
        u32 rhi = __shfl_xor(send_hi, 32);
        u32x4 bw;
        bw[0] = hi ? rlo : keep_lo;
        bw[1] = hi ? rhi : keep_hi;
        bw[2] = hi ? keep_lo : rlo;
        bw[3] = hi ? keep_hi : rhi;
        bf16x8 pf = __builtin_bit_cast(bf16x8, bw);
        bf16x8 vf = *(const bf16x8*)(Vg + l31 * 256 + kt2 * 32 + sb * 16 + hi * 8);
        o = MFMA32(vf, pf, o);
      }
    }
    lsum += __shfl_xor(lsum, 32);
    const float inv = 1.f / lsum;
    // normalize, transpose via per-wave LDS, store
#pragma unroll
    for (int qq = 0; qq < 4; ++qq) {
      *(u32*)(ob + l31 * 36 + 8 * qq + 4 * hi) =
          pack2(o[4 * qq] * inv, o[4 * qq + 1] * inv);
      *(u32*)(ob + l31 * 36 + 8 * qq + 4 * hi + 2) =
          pack2(o[4 * qq + 2] * inv, o[4 * qq + 3] * inv);
    }
    asm volatile("s_waitcnt lgkmcnt(0)" ::: "memory");
    __builtin_amdgcn_sched_barrier(0);
    int n2 = lane >> 1, ch = lane & 1;
    bf16x4 r0 = *(bf16x4*)(ob + n2 * 36 + ch * 16);
    bf16x4 r1 = *(bf16x4*)(ob + n2 * 36 + ch * 16 + 4);
    bf16x4 r2 = *(bf16x4*)(ob + n2 * 36 + ch * 16 + 8);
    bf16x4 r3 = *(bf16x4*)(ob + n2 * 36 + ch * 16 + 12);
    asm volatile("s_waitcnt lgkmcnt(0)" ::: "memory");
    __builtin_amdgcn_sched_barrier(0);
    bf16* dst = ao + (b * 256 + q0 + n2) * 256 + h * 32 + ch * 16;
    *(bf16x4*)dst = r0;
    *(bf16x4*)(dst + 4) = r1;
    *(bf16x4*)(dst + 8) = r2;
    *(bf16x4*)(dst + 12) = r3;
  }
}

// ---------------- output projection: block=(b, out-half), LDS-staged ao ----------------
__global__ __launch_bounds__(512) void k_proj(
    const bf16* __restrict__ ao, const bf16* __restrict__ Wp,
    const float* __restrict__ pb, float* __restrict__ out) {
  __shared__ bf16 Sl[2][16 * 264];  // 2 x 8,448 B
  const int b = blockIdx.x & 255;
  const int oh = blockIdx.x >> 8;
  const int tid = threadIdx.x;
  const int lane = tid & 63, wave = tid >> 6;
  const int l15 = lane & 15, l4 = lane >> 4;
  const int ot = oh * 8 + wave;
  bf16x8 af[8];
  const bf16* wr = Wp + (ot * 16 + l15) * 256 + l4 * 8;
#pragma unroll
  for (int kc = 0; kc < 8; ++kc) af[kc] = *(const bf16x8*)(wr + kc * 32);
  float bias[4];
#pragma unroll
  for (int r = 0; r < 4; ++r) bias[r] = pb[ot * 16 + l4 * 4 + r];
  const bf16* aob = ao + b * 65536;
  float* outb = out + b * 65536 + ot * 16 * 256;
  const int sr = tid >> 5, sc = (tid & 31) * 8;

  *(bf16x8*)(Sl[0] + sr * 264 + sc) = *(const bf16x8*)(aob + sr * 256 + sc);
  __syncthreads();

  const f32x4 fz = {0.f, 0.f, 0.f, 0.f};
  for (int nt = 0; nt < 16; ++nt) {
    const int cur = nt & 1;
    if (nt < 15)
      *(bf16x8*)(Sl[cur ^ 1] + sr * 264 + sc) =
          *(const bf16x8*)(aob + ((nt + 1) * 16 + sr) * 256 + sc);
    f32x4 acc = fz;
#pragma unroll
    for (int kc = 0; kc < 8; ++kc) {
      bf16x8 bfr = *(const bf16x8*)(Sl[cur] + l15 * 264 + kc * 32 + l4 * 8);
      acc = MFMA16(af[kc], bfr, acc);
    }
#pragma unroll
    for (int r = 0; r < 4; ++r)
      outb[(l4 * 4 + r) * 256 + nt * 16 + l15] = acc[r] + bias[r];
    __syncthreads();
  }
}

extern "C" void kernel_launch(void* const* d_in, const int* in_sizes, int n_in,
                              void* d_out, int out_size, void* d_ws, size_t ws_size,
                              hipStream_t stream) {
  const float* x    = (const float*)d_in[0];
  const float* qkvw = (const float*)d_in[1];
  const float* qkvb = (const float*)d_in[2];
  const float* pjw  = (const float*)d_in[3];
  const float* pjb  = (const float*)d_in[4];
  const float* ppw  = (const float*)d_in[5];
  const float* ppb  = (const float*)d_in[6];
  const float* g1 = (const float*)d_in[7];   const float* b1 = (const float*)d_in[8];
  const float* f1w = (const float*)d_in[9];  const float* f1b = (const float*)d_in[10];
  const float* g2 = (const float*)d_in[11];  const float* b2 = (const float*)d_in[12];
  const float* f2w = (const float*)d_in[13]; const float* f2b = (const float*)d_in[14];
  const float* g3 = (const float*)d_in[15];  const float* b3 = (const float*)d_in[16];
  const float* f3w = (const float*)d_in[17]; const float* f3b = (const float*)d_in[18];
  float* out = (float*)d_out;

  // ws: q | k | vT | ao (16,777,216 bf16 each) | ptab 8192 f32 | Wf 196608 bf16
  //     | Wproj 65536 bf16 | Bsw 524288 bf16
  bf16* wsq  = (bf16*)d_ws;
  bf16* wsk  = wsq + 16777216;
  bf16* wsv  = wsk + 16777216;
  bf16* wsao = wsv + 16777216;
  float* ptab = (float*)(wsao + 16777216);
  bf16* wqkv = (bf16*)(ptab + 8192);
  bf16* wpj  = wqkv + 196608;
  bf16* bsw  = wpj + 65536;

  hipLaunchKernelGGL(k_prep, dim3(164), dim3(256), 0, stream, qkvw, wqkv, pjw,
                     wpj, ppw, ppb, g1, b1, f1w, f1b, g2, b2, f2w, f2b, g3, b3,
                     f3w, f3b, ptab);
  hipLaunchKernelGGL(k_bias, dim3(128), dim3(256), 0, stream, ptab, bsw);
  hipLaunchKernelGGL(k_qkv, dim3(512), dim3(512), 0, stream, x, wqkv, qkvb, wsq,
                     wsk, wsv);
  hipLaunchKernelGGL(k_attn, dim3(2048), dim3(256), 0, stream, wsq, wsk, wsv,
                     bsw, wsao);
  hipLaunchKernelGGL(k_proj, dim3(512), dim3(512), 0, stream, wsao, wpj, pjb, out);
}

// Round 20
// 159.418 us; speedup vs baseline: 1.0328x; 1.0328x over previous
//
#include <hip/hip_runtime.h>

typedef __bf16 bf16;
typedef __bf16 bf16x8 __attribute__((ext_vector_type(8)));
typedef __bf16 bf16x4 __attribute__((ext_vector_type(4)));
typedef float f32x4 __attribute__((ext_vector_type(4)));
typedef float f32x16 __attribute__((ext_vector_type(16)));
typedef unsigned int u32;
typedef unsigned int u32x2 __attribute__((ext_vector_type(2)));
typedef unsigned int u32x4 __attribute__((ext_vector_type(4)));

#define MFMA16(a, b, c) __builtin_amdgcn_mfma_f32_16x16x32_bf16(a, b, c, 0, 0, 0)
#define MFMA32(a, b, c) __builtin_amdgcn_mfma_f32_32x32x16_bf16(a, b, c, 0, 0, 0)

__device__ __forceinline__ u32 pack2(float a, float b) {
  unsigned short ua = __builtin_bit_cast(unsigned short, (bf16)a);
  unsigned short ub = __builtin_bit_cast(unsigned short, (bf16)b);
  return (u32)ua | ((u32)ub << 16);
}

__device__ __forceinline__ void lnrelu16(const float* in, float* out,
                                         const float* __restrict__ g,
                                         const float* __restrict__ b) {
  float mu = 0.f;
#pragma unroll
  for (int t = 0; t < 16; ++t) mu += in[t];
  mu *= 0.0625f;
  float var = 0.f;
#pragma unroll
  for (int t = 0; t < 16; ++t) { float d = in[t] - mu; var += d * d; }
  var *= 0.0625f;
  float inv = rsqrtf(var + 1e-5f);
#pragma unroll
  for (int t = 0; t < 16; ++t) {
    float v = (in[t] - mu) * inv * g[t] + b[t];
    out[t] = fmaxf(v, 0.f);
  }
}

// ---------------- merged prep: wpack (blk 0-95) | proj cvt (96-159) | dpb (160-163) ----------------
__global__ __launch_bounds__(256) void k_prep(
    const float* __restrict__ qkvw, bf16* __restrict__ wqkv,
    const float* __restrict__ pjw, bf16* __restrict__ wpj,
    const float* __restrict__ ppw, const float* __restrict__ ppb,
    const float* __restrict__ g1, const float* __restrict__ b1,
    const float* __restrict__ f1w, const float* __restrict__ f1b,
    const float* __restrict__ g2, const float* __restrict__ b2,
    const float* __restrict__ f2w, const float* __restrict__ f2b,
    const float* __restrict__ g3, const float* __restrict__ b3,
    const float* __restrict__ f3w, const float* __restrict__ f3b,
    float* __restrict__ ptab) {
  const int blk = blockIdx.x;
  if (blk < 96) {
    // qkv_w -> B-fragment-major pack: Wf[(ot*8+kc)*64+lane][8]
    int t = blk * 256 + threadIdx.x;
    int lane = t & 63, fk = t >> 6;
    int ot = fk >> 3, kc = fk & 7;
    int o = ot * 16 + (lane & 15), cb = kc * 32 + (lane >> 4) * 8;
    const float* src = qkvw + o * 256 + cb;
    bf16x8 v;
#pragma unroll
    for (int j = 0; j < 8; ++j) v[j] = (bf16)src[j];
    *(bf16x8*)(wqkv + (size_t)t * 8) = v;
  } else if (blk < 160) {
    // proj_w fp32 -> bf16
    int i = (blk - 96) * 256 + threadIdx.x;
    if (i < 16384) {
      float4 v = ((const float4*)pjw)[i];
      bf16x4 o;
      o[0] = (bf16)v.x; o[1] = (bf16)v.y; o[2] = (bf16)v.z; o[3] = (bf16)v.w;
      ((bf16x4*)wpj)[i] = o;
    }
  } else {
    // dynamic position-bias MLP (961 rows)
    int l = (blk - 160) * 256 + threadIdx.x;
    if (l >= 961) return;
    float dh = (float)(l / 31) - 15.f;
    float dw = (float)(l % 31) - 15.f;
    float p[16], a[16], y[16];
#pragma unroll
    for (int t = 0; t < 16; ++t)
      p[t] = dh * ppw[2 * t] + dw * ppw[2 * t + 1] + ppb[t];
    lnrelu16(p, a, g1, b1);
#pragma unroll
    for (int t = 0; t < 16; ++t) {
      float s = f1b[t];
#pragma unroll
      for (int u = 0; u < 16; ++u) s += a[u] * f1w[t * 16 + u];
      y[t] = s;
    }
    lnrelu16(y, a, g2, b2);
#pragma unroll
    for (int t = 0; t < 16; ++t) {
      float s = f2b[t];
#pragma unroll
      for (int u = 0; u < 16; ++u) s += a[u] * f2w[t * 16 + u];
      p[t] = s;
    }
    lnrelu16(p, a, g3, b3);
#pragma unroll
    for (int t = 0; t < 8; ++t) {
      float s = f3b[t];
#pragma unroll
      for (int u = 0; u < 16; ++u) s += a[u] * f3w[t * 16 + u];
      ptab[l * 8 + t] = s;
    }
  }
}

// ---------------- bias table (bf16) in 32x32 MFMA D-fragment order ----------------
__global__ __launch_bounds__(256) void k_bias(const float* __restrict__ ptab,
                                              bf16* __restrict__ Bsw) {
  int idx = blockIdx.x * 256 + threadIdx.x;  // 128 blocks -> 32768 threads
  int lane = idx & 63, tg = idx >> 6;        // tg 0..511
  int h = tg >> 6, qt = (tg >> 3) & 7, kt2 = tg & 7;
  int l31 = lane & 31, hi2 = lane >> 5;
  int n = qt * 32 + l31;
  int i1 = n >> 4, j1 = n & 15;
  bf16x8 o0, o1;
#pragma unroll
  for (int reg = 0; reg < 16; ++reg) {
    int key = kt2 * 32 + (reg & 3) + 8 * (reg >> 2) + 4 * hi2;
    int i2 = key >> 4, j2 = key & 15;
    int li = (i1 - i2 + 15) * 31 + (j1 - j2 + 15);
    bf16 v = (bf16)ptab[li * 8 + h];
    if (reg < 8) o0[reg] = v; else o1[reg - 8] = v;
  }
  bf16* dst = Bsw + tg * 1024 + lane * 16;
  *(bf16x8*)dst = o0;
  *(bf16x8*)(dst + 8) = o1;
}

// ---------------- qkv GEMM: (B*N,256) x (768,256)^T ----------------
// R19 structure; staging loads issued ALL UPFRONT into registers (T14
// issue-early) so the 16 HBM loads pipeline instead of serializing behind
// each iteration's shuffle chain.
__global__ __launch_bounds__(512) void k_qkv(
    const float* __restrict__ x, const bf16* __restrict__ Wf,
    const float* __restrict__ qb, bf16* __restrict__ q, bf16* __restrict__ kk,
    bf16* __restrict__ vT) {
  __shared__ bf16 Xl[128 * 256];   // 65,536 B, swizzled [n][c]
  __shared__ bf16 Vb[8][16 * 36];  // 9,216 B: per-wave bounce (v AND q/k)
  const int b = blockIdx.x >> 1;
  const int nh = blockIdx.x & 1;
  const int tid = threadIdx.x;
  const int lane = tid & 63;
  const int wave = tid >> 6;
  const int wm = wave & 1, wo = wave >> 1;
  const int l15 = lane & 15, l4 = lane >> 4;
  const int n0w = nh * 128 + wm * 64;

  // ---- stage x[b][c][nh*128+n] -> Xl[n][c]: issue-early loads, then
  //      quad-transpose + swizzled writes ----
  {
    const float* xb = x + b * 65536 + nh * 128;
    const int p = tid & 3;
    const int Q = tid >> 2;
    const int n0 = (Q & 31) * 4;
    const int cgb = Q >> 5;  // 0..3
    float4 vv[16];
#pragma unroll
    for (int it = 0; it < 16; ++it) {
      const int c0 = (cgb + it * 4) * 4;
      vv[it] = *(const float4*)(xb + (c0 + p) * 256 + n0);
    }
#pragma unroll
    for (int it = 0; it < 16; ++it) {
      const int c0 = (cgb + it * 4) * 4;
      float4 v = vv[it];
      u32 u0 = pack2(v.x, v.y);
      u32 u1 = pack2(v.z, v.w);
      u32 su0 = __shfl_xor(u0, 1);
      u32 su1 = __shfl_xor(u1, 1);
      u32 w, z;
      if (p & 1) {
        w = (su0 >> 16) | (u0 & 0xffff0000u);
        z = (su1 >> 16) | (u1 & 0xffff0000u);
      } else {
        w = (u0 & 0xffffu) | (su0 << 16);
        z = (u1 & 0xffffu) | (su1 << 16);
      }
      u32 sw = __shfl_xor(w, 2);
      u32 sz = __shfl_xor(z, 2);
      u32x2 o2;
      o2[0] = (p & 2) ? sz : w;
      o2[1] = (p & 2) ? z : sw;
      const int n = n0 + p;
      const int wb = (2 * c0) ^ ((n & 7) << 4);
      *(u32x2*)((char*)Xl + n * 512 + wb) = o2;
    }
  }
  __syncthreads();

  const f32x4 fz = {0.f, 0.f, 0.f, 0.f};
  bf16* lb = Vb[wave];
  for (int og = 0; og < 3; ++og) {
    const int ot0 = wo * 12 + og * 4;
    f32x4 acc[4][4];  // [nt][oi]
#pragma unroll
    for (int nt = 0; nt < 4; ++nt)
#pragma unroll
      for (int oi = 0; oi < 4; ++oi) acc[nt][oi] = fz;

    bf16x8 afr[2][4], bfr[2][4];
#pragma unroll
    for (int nt = 0; nt < 4; ++nt) {
      int nn = wm * 64 + nt * 16 + l15;
      int wb = (l4 * 16) ^ ((nn & 7) << 4);
      afr[0][nt] = *(const bf16x8*)((const char*)Xl + nn * 512 + wb);
    }
#pragma unroll
    for (int oi = 0; oi < 4; ++oi)
      bfr[0][oi] = *(const bf16x8*)(Wf + (((ot0 + oi) * 8) * 64 + lane) * 8);

#pragma unroll
    for (int kc = 0; kc < 8; ++kc) {
      const int cur = kc & 1, nxt = cur ^ 1;
      if (kc < 7) {
#pragma unroll
        for (int nt = 0; nt < 4; ++nt) {
          int nn = wm * 64 + nt * 16 + l15;
          int wb = ((kc + 1) * 64 + l4 * 16) ^ ((nn & 7) << 4);
          afr[nxt][nt] = *(const bf16x8*)((const char*)Xl + nn * 512 + wb);
        }
#pragma unroll
        for (int oi = 0; oi < 4; ++oi)
          bfr[nxt][oi] =
              *(const bf16x8*)(Wf + ((((ot0 + oi) * 8) + kc + 1) * 64 + lane) * 8);
      }
#pragma unroll
      for (int nt = 0; nt < 4; ++nt)
#pragma unroll
        for (int oi = 0; oi < 4; ++oi)
          acc[nt][oi] = MFMA16(afr[cur][nt], bfr[cur][oi], acc[nt][oi]);
    }

    // ---- epilogue; each (wo,og) group lies entirely in one segment ----
    const int seg = ot0 >> 4;  // 0=q 1=k 2=v
    if (seg < 2) {
      bf16* dstbuf = (seg == 0) ? q : kk;
      const float scale = (seg == 0) ? 0.17677669529663687f : 1.0f;
#pragma unroll
      for (int p = 0; p < 2; ++p) {  // head-pair: oi (2p, 2p+1) = full 32 d
        int ot = ot0 + 2 * p;
        int h = (ot >> 1) & 7;
        int base = (b * 8 + h) * 8192;
        float bias0 = qb[seg * 256 + h * 32 + l15];
        float bias1 = qb[seg * 256 + h * 32 + 16 + l15];
#pragma unroll
        for (int nt = 0; nt < 4; ++nt) {
          // 16 rows x 32 d tile into [16][36] bounce (2-way-free banks)
#pragma unroll
          for (int r = 0; r < 4; ++r) {
            int row = l4 * 4 + r;
            lb[row * 36 + l15] = (bf16)((acc[nt][2 * p][r] + bias0) * scale);
            lb[row * 36 + 16 + l15] =
                (bf16)((acc[nt][2 * p + 1][r] + bias1) * scale);
          }
          asm volatile("s_waitcnt lgkmcnt(0)" ::: "memory");
          __builtin_amdgcn_sched_barrier(0);
          int row = lane >> 2, ch = lane & 3;
          bf16x8 tv = *(const bf16x8*)(lb + row * 36 + ch * 8);
          asm volatile("s_waitcnt lgkmcnt(0)" ::: "memory");
          __builtin_amdgcn_sched_barrier(0);
          // 64 lanes x 16B = 1KB contiguous ([n][32] rows are contiguous)
          *(bf16x8*)(dstbuf + base + (n0w + nt * 16 + row) * 32 + ch * 8) = tv;
        }
      }
    } else {
      // v: transpose 16d x 32n tiles through LDS -> vT[d][n] 64B rows
#pragma unroll
      for (int oi = 0; oi < 4; ++oi) {
        int ot = ot0 + oi;
        int o = ot * 16 + l15;
        float bias = qb[o];
        int h = (o >> 5) & 7;
        int d = o & 31;
        int base = (b * 8 + h) * 8192;
#pragma unroll
        for (int pr = 0; pr < 2; ++pr) {
          f32x4 acc0 = acc[2 * pr][oi], acc1 = acc[2 * pr + 1][oi];
          int n0p = n0w + pr * 32;
#pragma unroll
          for (int nt = 0; nt < 2; ++nt) {
            f32x4 a = nt ? acc1 : acc0;
            *(u32*)(lb + l15 * 36 + nt * 16 + l4 * 4) =
                pack2(a[0] + bias, a[1] + bias);
            *(u32*)(lb + l15 * 36 + nt * 16 + l4 * 4 + 2) =
                pack2(a[2] + bias, a[3] + bias);
          }
          asm volatile("s_waitcnt lgkmcnt(0)" ::: "memory");
          __builtin_amdgcn_sched_barrier(0);
          int dl = lane >> 2, chv = lane & 3;
          bf16x4 rv0 = *(bf16x4*)(lb + dl * 36 + chv * 8);
          bf16x4 rv1 = *(bf16x4*)(lb + dl * 36 + chv * 8 + 4);
          asm volatile("s_waitcnt lgkmcnt(0)" ::: "memory");
          __builtin_amdgcn_sched_barrier(0);
          int d2 = (ot & 1) * 16 + dl;
          bf16* dv2 = vT + base + d2 * 256 + n0p + chv * 8;
          *(bf16x4*)dv2 = rv0;
          *(bf16x4*)(dv2 + 4) = rv1;
        }
      }
    }
  }
}

// ---------------- attention per (b, h): fused QK->exp->PV per kt2 ----------------
__global__ __launch_bounds__(256, 4) void k_attn(
    const bf16* __restrict__ q, const bf16* __restrict__ kk,
    const bf16* __restrict__ vT, const bf16* __restrict__ Bsw,
    bf16* __restrict__ ao) {
  __shared__ bf16 Kl[256 * 36];    // 18,432 B
  __shared__ bf16 Ob[4][32 * 36];  // 9,216 B: per-wave output transpose bounce
  const int bh = blockIdx.x;
  const int b = bh >> 3, h = bh & 7;
  const int tid = threadIdx.x;
  const int lane = tid & 63, wave = tid >> 6;
  const int l31 = lane & 31, hi = lane >> 5;

  const bf16* Kg = kk + bh * 8192;
#pragma unroll
  for (int i = 0; i < 4; ++i) {
    int t = tid + i * 256;
    int n = t >> 2, dc = t & 3;
    *(bf16x8*)(Kl + n * 36 + dc * 8) = *(const bf16x8*)(Kg + n * 32 + dc * 8);
  }
  __syncthreads();

  const bf16* Vg = vT + bh * 8192;
  bf16* ob = Ob[wave];
  for (int qi = 0; qi < 2; ++qi) {
    const int qt = wave * 2 + qi, q0 = qt * 32;
    bf16x8 qf0 = *(const bf16x8*)(q + bh * 8192 + (q0 + l31) * 32 + hi * 8);
    bf16x8 qf1 = *(const bf16x8*)(q + bh * 8192 + (q0 + l31) * 32 + 16 + hi * 8);
    const bf16* bq = Bsw + (h * 8 + qt) * 8192 + lane * 16;
    float lsum = 0.f;
    f32x16 o;
#pragma unroll
    for (int i = 0; i < 16; ++i) o[i] = 0.f;
#pragma unroll
    for (int kt2 = 0; kt2 < 8; ++kt2) {
      u32x4 w0 = *(const u32x4*)(bq + kt2 * 1024);       // bias regs 0..7
      u32x4 w1 = *(const u32x4*)(bq + kt2 * 1024 + 8);   // bias regs 8..15
      f32x16 acc;
#pragma unroll
      for (int j = 0; j < 4; ++j) {
        acc[2 * j] = __builtin_bit_cast(float, w0[j] << 16);
        acc[2 * j + 1] = __builtin_bit_cast(float, w0[j] & 0xffff0000u);
        acc[8 + 2 * j] = __builtin_bit_cast(float, w1[j] << 16);
        acc[8 + 2 * j + 1] = __builtin_bit_cast(float, w1[j] & 0xffff0000u);
      }
      bf16x8 kf0 = *(const bf16x8*)(Kl + (kt2 * 32 + l31) * 36 + hi * 8);
      bf16x8 kf1 = *(const bf16x8*)(Kl + (kt2 * 32 + l31) * 36 + 16 + hi * 8);
      acc = MFMA32(kf0, qf0, acc);
      acc = MFMA32(kf1, qf1, acc);
      // exp (no max-shift) + pack; P for this kt2 feeds PV immediately
      u32 lo[4], hw[4];
#pragma unroll
      for (int qq = 0; qq < 4; ++qq) {
        float e0 = __expf(acc[4 * qq]);
        float e1 = __expf(acc[4 * qq + 1]);
        float e2 = __expf(acc[4 * qq + 2]);
        float e3 = __expf(acc[4 * qq + 3]);
        lsum += (e0 + e1) + (e2 + e3);
        lo[qq] = pack2(e0, e1);
        hw[qq] = pack2(e2, e3);
      }
#pragma unroll
      for (int sb = 0; sb < 2; ++sb) {
        u32 keep_lo = hi ? lo[2 * sb + 1] : lo[2 * sb];
        u32 keep_hi = hi ? hw[2 * sb + 1] : hw[2 * sb];
        u32 send_lo = hi ? lo[2 * sb] : lo[2 * sb + 1];
        u32 send_hi = hi ? hw[2 * sb] : hw[2 * sb + 1];
        u32 rlo = __shfl_xor(send_lo, 32);
        u32 rhi = __shfl_xor(send_hi, 32);
        u32x4 bw;
        bw[0] = hi ? rlo : keep_lo;
        bw[1] = hi ? rhi : keep_hi;
        bw[2] = hi ? keep_lo : rlo;
        bw[3] = hi ? keep_hi : rhi;
        bf16x8 pf = __builtin_bit_cast(bf16x8, bw);
        bf16x8 vf = *(const bf16x8*)(Vg + l31 * 256 + kt2 * 32 + sb * 16 + hi * 8);
        o = MFMA32(vf, pf, o);
      }
    }
    lsum += __shfl_xor(lsum, 32);
    const float inv = 1.f / lsum;
    // normalize, transpose via per-wave LDS, store
#pragma unroll
    for (int qq = 0; qq < 4; ++qq) {
      *(u32*)(ob + l31 * 36 + 8 * qq + 4 * hi) =
          pack2(o[4 * qq] * inv, o[4 * qq + 1] * inv);
      *(u32*)(ob + l31 * 36 + 8 * qq + 4 * hi + 2) =
          pack2(o[4 * qq + 2] * inv, o[4 * qq + 3] * inv);
    }
    asm volatile("s_waitcnt lgkmcnt(0)" ::: "memory");
    __builtin_amdgcn_sched_barrier(0);
    int n2 = lane >> 1, ch = lane & 1;
    bf16x4 r0 = *(bf16x4*)(ob + n2 * 36 + ch * 16);
    bf16x4 r1 = *(bf16x4*)(ob + n2 * 36 + ch * 16 + 4);
    bf16x4 r2 = *(bf16x4*)(ob + n2 * 36 + ch * 16 + 8);
    bf16x4 r3 = *(bf16x4*)(ob + n2 * 36 + ch * 16 + 12);
    asm volatile("s_waitcnt lgkmcnt(0)" ::: "memory");
    __builtin_amdgcn_sched_barrier(0);
    bf16* dst = ao + (b * 256 + q0 + n2) * 256 + h * 32 + ch * 16;
    *(bf16x4*)dst = r0;
    *(bf16x4*)(dst + 4) = r1;
    *(bf16x4*)(dst + 8) = r2;
    *(bf16x4*)(dst + 12) = r3;
  }
}

// ---------------- output projection: block=(b, out-half), LDS-staged ao ----------------
__global__ __launch_bounds__(512) void k_proj(
    const bf16* __restrict__ ao, const bf16* __restrict__ Wp,
    const float* __restrict__ pb, float* __restrict__ out) {
  __shared__ bf16 Sl[2][16 * 264];  // 2 x 8,448 B
  const int b = blockIdx.x & 255;
  const int oh = blockIdx.x >> 8;
  const int tid = threadIdx.x;
  const int lane = tid & 63, wave = tid >> 6;
  const int l15 = lane & 15, l4 = lane >> 4;
  const int ot = oh * 8 + wave;
  bf16x8 af[8];
  const bf16* wr = Wp + (ot * 16 + l15) * 256 + l4 * 8;
#pragma unroll
  for (int kc = 0; kc < 8; ++kc) af[kc] = *(const bf16x8*)(wr + kc * 32);
  float bias[4];
#pragma unroll
  for (int r = 0; r < 4; ++r) bias[r] = pb[ot * 16 + l4 * 4 + r];
  const bf16* aob = ao + b * 65536;
  float* outb = out + b * 65536 + ot * 16 * 256;
  const int sr = tid >> 5, sc = (tid & 31) * 8;

  *(bf16x8*)(Sl[0] + sr * 264 + sc) = *(const bf16x8*)(aob + sr * 256 + sc);
  __syncthreads();

  const f32x4 fz = {0.f, 0.f, 0.f, 0.f};
  for (int nt = 0; nt < 16; ++nt) {
    const int cur = nt & 1;
    if (nt < 15)
      *(bf16x8*)(Sl[cur ^ 1] + sr * 264 + sc) =
          *(const bf16x8*)(aob + ((nt + 1) * 16 + sr) * 256 + sc);
    f32x4 acc = fz;
#pragma unroll
    for (int kc = 0; kc < 8; ++kc) {
      bf16x8 bfr = *(const bf16x8*)(Sl[cur] + l15 * 264 + kc * 32 + l4 * 8);
      acc = MFMA16(af[kc], bfr, acc);
    }
#pragma unroll
    for (int r = 0; r < 4; ++r)
      outb[(l4 * 4 + r) * 256 + nt * 16 + l15] = acc[r] + bias[r];
    __syncthreads();
  }
}

extern "C" void kernel_launch(void* const* d_in, const int* in_sizes, int n_in,
                              void* d_out, int out_size, void* d_ws, size_t ws_size,
                              hipStream_t stream) {
  const float* x    = (const float*)d_in[0];
  const float* qkvw = (const float*)d_in[1];
  const float* qkvb = (const float*)d_in[2];
  const float* pjw  = (const float*)d_in[3];
  const float* pjb  = (const float*)d_in[4];
  const float* ppw  = (const float*)d_in[5];
  const float* ppb  = (const float*)d_in[6];
  const float* g1 = (const float*)d_in[7];   const float* b1 = (const float*)d_in[8];
  const float* f1w = (const float*)d_in[9];  const float* f1b = (const float*)d_in[10];
  const float* g2 = (const float*)d_in[11];  const float* b2 = (const float*)d_in[12];
  const float* f2w = (const float*)d_in[13]; const float* f2b = (const float*)d_in[14];
  const float* g3 = (const float*)d_in[15];  const float* b3 = (const float*)d_in[16];
  const float* f3w = (const float*)d_in[17]; const float* f3b = (const float*)d_in[18];
  float* out = (float*)d_out;

  // ws: q | k | vT | ao (16,777,216 bf16 each) | ptab 8192 f32 | Wf 196608 bf16
  //     | Wproj 65536 bf16 | Bsw 524288 bf16
  bf16* wsq  = (bf16*)d_ws;
  bf16* wsk  = wsq + 16777216;
  bf16* wsv  = wsk + 16777216;
  bf16* wsao = wsv + 16777216;
  float* ptab = (float*)(wsao + 16777216);
  bf16* wqkv = (bf16*)(ptab + 8192);
  bf16* wpj  = wqkv + 196608;
  bf16* bsw  = wpj + 65536;

  hipLaunchKernelGGL(k_prep, dim3(164), dim3(256), 0, stream, qkvw, wqkv, pjw,
                     wpj, ppw, ppb, g1, b1, f1w, f1b, g2, b2, f2w, f2b, g3, b3,
                     f3w, f3b, ptab);
  hipLaunchKernelGGL(k_bias, dim3(128), dim3(256), 0, stream, ptab, bsw);
  hipLaunchKernelGGL(k_qkv, dim3(512), dim3(512), 0, stream, x, wqkv, qkvb, wsq,
                     wsk, wsv);
  hipLaunchKernelGGL(k_attn, dim3(2048), dim3(256), 0, stream, wsq, wsk, wsv,
                     bsw, wsao);
  hipLaunchKernelGGL(k_proj, dim3(512), dim3(512), 0, stream, wsao, wpj, pjb, out);
}

// Round 21
// 156.158 us; speedup vs baseline: 1.0543x; 1.0209x over previous
//
#include <hip/hip_runtime.h>

typedef __bf16 bf16;
typedef __bf16 bf16x8 __attribute__((ext_vector_type(8)));
typedef __bf16 bf16x4 __attribute__((ext_vector_type(4)));
typedef float f32x4 __attribute__((ext_vector_type(4)));
typedef float f32x16 __attribute__((ext_vector_type(16)));
typedef unsigned int u32;
typedef unsigned int u32x2 __attribute__((ext_vector_type(2)));
typedef unsigned int u32x4 __attribute__((ext_vector_type(4)));

#define MFMA16(a, b, c) __builtin_amdgcn_mfma_f32_16x16x32_bf16(a, b, c, 0, 0, 0)
#define MFMA32(a, b, c) __builtin_amdgcn_mfma_f32_32x32x16_bf16(a, b, c, 0, 0, 0)

__device__ __forceinline__ u32 pack2(float a, float b) {
  unsigned short ua = __builtin_bit_cast(unsigned short, (bf16)a);
  unsigned short ub = __builtin_bit_cast(unsigned short, (bf16)b);
  return (u32)ua | ((u32)ub << 16);
}

__device__ __forceinline__ void lnrelu16(const float* in, float* out,
                                         const float* __restrict__ g,
                                         const float* __restrict__ b) {
  float mu = 0.f;
#pragma unroll
  for (int t = 0; t < 16; ++t) mu += in[t];
  mu *= 0.0625f;
  float var = 0.f;
#pragma unroll
  for (int t = 0; t < 16; ++t) { float d = in[t] - mu; var += d * d; }
  var *= 0.0625f;
  float inv = rsqrtf(var + 1e-5f);
#pragma unroll
  for (int t = 0; t < 16; ++t) {
    float v = (in[t] - mu) * inv * g[t] + b[t];
    out[t] = fmaxf(v, 0.f);
  }
}

// ---------------- merged prep: wpack (blk 0-95) | proj cvt (96-159) | dpb (160-163) ----------------
__global__ __launch_bounds__(256) void k_prep(
    const float* __restrict__ qkvw, bf16* __restrict__ wqkv,
    const float* __restrict__ pjw, bf16* __restrict__ wpj,
    const float* __restrict__ ppw, const float* __restrict__ ppb,
    const float* __restrict__ g1, const float* __restrict__ b1,
    const float* __restrict__ f1w, const float* __restrict__ f1b,
    const float* __restrict__ g2, const float* __restrict__ b2,
    const float* __restrict__ f2w, const float* __restrict__ f2b,
    const float* __restrict__ g3, const float* __restrict__ b3,
    const float* __restrict__ f3w, const float* __restrict__ f3b,
    float* __restrict__ ptab) {
  const int blk = blockIdx.x;
  if (blk < 96) {
    // qkv_w -> B-fragment-major pack: Wf[(ot*8+kc)*64+lane][8]
    int t = blk * 256 + threadIdx.x;
    int lane = t & 63, fk = t >> 6;
    int ot = fk >> 3, kc = fk & 7;
    int o = ot * 16 + (lane & 15), cb = kc * 32 + (lane >> 4) * 8;
    const float* src = qkvw + o * 256 + cb;
    bf16x8 v;
#pragma unroll
    for (int j = 0; j < 8; ++j) v[j] = (bf16)src[j];
    *(bf16x8*)(wqkv + (size_t)t * 8) = v;
  } else if (blk < 160) {
    // proj_w fp32 -> bf16
    int i = (blk - 96) * 256 + threadIdx.x;
    if (i < 16384) {
      float4 v = ((const float4*)pjw)[i];
      bf16x4 o;
      o[0] = (bf16)v.x; o[1] = (bf16)v.y; o[2] = (bf16)v.z; o[3] = (bf16)v.w;
      ((bf16x4*)wpj)[i] = o;
    }
  } else {
    // dynamic position-bias MLP (961 rows)
    int l = (blk - 160) * 256 + threadIdx.x;
    if (l >= 961) return;
    float dh = (float)(l / 31) - 15.f;
    float dw = (float)(l % 31) - 15.f;
    float p[16], a[16], y[16];
#pragma unroll
    for (int t = 0; t < 16; ++t)
      p[t] = dh * ppw[2 * t] + dw * ppw[2 * t + 1] + ppb[t];
    lnrelu16(p, a, g1, b1);
#pragma unroll
    for (int t = 0; t < 16; ++t) {
      float s = f1b[t];
#pragma unroll
      for (int u = 0; u < 16; ++u) s += a[u] * f1w[t * 16 + u];
      y[t] = s;
    }
    lnrelu16(y, a, g2, b2);
#pragma unroll
    for (int t = 0; t < 16; ++t) {
      float s = f2b[t];
#pragma unroll
      for (int u = 0; u < 16; ++u) s += a[u] * f2w[t * 16 + u];
      p[t] = s;
    }
    lnrelu16(p, a, g3, b3);
#pragma unroll
    for (int t = 0; t < 8; ++t) {
      float s = f3b[t];
#pragma unroll
      for (int u = 0; u < 16; ++u) s += a[u] * f3w[t * 16 + u];
      ptab[l * 8 + t] = s;
    }
  }
}

// ---------------- bias table (bf16) in 32x32 MFMA D-fragment order ----------------
__global__ __launch_bounds__(256) void k_bias(const float* __restrict__ ptab,
                                              bf16* __restrict__ Bsw) {
  int idx = blockIdx.x * 256 + threadIdx.x;  // 128 blocks -> 32768 threads
  int lane = idx & 63, tg = idx >> 6;        // tg 0..511
  int h = tg >> 6, qt = (tg >> 3) & 7, kt2 = tg & 7;
  int l31 = lane & 31, hi2 = lane >> 5;
  int n = qt * 32 + l31;
  int i1 = n >> 4, j1 = n & 15;
  bf16x8 o0, o1;
#pragma unroll
  for (int reg = 0; reg < 16; ++reg) {
    int key = kt2 * 32 + (reg & 3) + 8 * (reg >> 2) + 4 * hi2;
    int i2 = key >> 4, j2 = key & 15;
    int li = (i1 - i2 + 15) * 31 + (j1 - j2 + 15);
    bf16 v = (bf16)ptab[li * 8 + h];
    if (reg < 8) o0[reg] = v; else o1[reg - 8] = v;
  }
  bf16* dst = Bsw + tg * 1024 + lane * 16;
  *(bf16x8*)dst = o0;
  *(bf16x8*)(dst + 8) = o1;
}

// ---------------- qkv GEMM: (B*N,256) x (768,256)^T ----------------
// Wave decomposition: 8 waves x (6 distinct ot x all 128 rows) -> zero
// duplicated B-fragment reads (was 2x: wm-pairs read identical bfr).
// acc[8][2]: 8 LDS A-frags + 2 L2 B-frags per kc, same 384 MFMA/wave.
__global__ __launch_bounds__(512) void k_qkv(
    const float* __restrict__ x, const bf16* __restrict__ Wf,
    const float* __restrict__ qb, bf16* __restrict__ q, bf16* __restrict__ kk,
    bf16* __restrict__ vT) {
  __shared__ bf16 Xl[128 * 256];   // 65,536 B, swizzled [n][c]
  __shared__ bf16 Vb[8][16 * 36];  // 9,216 B: per-wave bounce (v AND q/k)
  const int b = blockIdx.x >> 1;
  const int nh = blockIdx.x & 1;
  const int tid = threadIdx.x;
  const int lane = tid & 63;
  const int wave = tid >> 6;
  const int l15 = lane & 15, l4 = lane >> 4;
  const int n0w = nh * 128;

  // ---- stage x[b][c][nh*128+n] -> Xl[n][c]: issue-early loads, then
  //      quad-transpose + swizzled writes ----
  {
    const float* xb = x + b * 65536 + nh * 128;
    const int p = tid & 3;
    const int Q = tid >> 2;
    const int n0 = (Q & 31) * 4;
    const int cgb = Q >> 5;  // 0..3
    float4 vv[16];
#pragma unroll
    for (int it = 0; it < 16; ++it) {
      const int c0 = (cgb + it * 4) * 4;
      vv[it] = *(const float4*)(xb + (c0 + p) * 256 + n0);
    }
#pragma unroll
    for (int it = 0; it < 16; ++it) {
      const int c0 = (cgb + it * 4) * 4;
      float4 v = vv[it];
      u32 u0 = pack2(v.x, v.y);
      u32 u1 = pack2(v.z, v.w);
      u32 su0 = __shfl_xor(u0, 1);
      u32 su1 = __shfl_xor(u1, 1);
      u32 w, z;
      if (p & 1) {
        w = (su0 >> 16) | (u0 & 0xffff0000u);
        z = (su1 >> 16) | (u1 & 0xffff0000u);
      } else {
        w = (u0 & 0xffffu) | (su0 << 16);
        z = (u1 & 0xffffu) | (su1 << 16);
      }
      u32 sw = __shfl_xor(w, 2);
      u32 sz = __shfl_xor(z, 2);
      u32x2 o2;
      o2[0] = (p & 2) ? sz : w;
      o2[1] = (p & 2) ? z : sw;
      const int n = n0 + p;
      const int wb = (2 * c0) ^ ((n & 7) << 4);
      *(u32x2*)((char*)Xl + n * 512 + wb) = o2;
    }
  }
  __syncthreads();

  const f32x4 fz = {0.f, 0.f, 0.f, 0.f};
  bf16* lb = Vb[wave];
  for (int og = 0; og < 3; ++og) {
    const int ot0 = wave * 6 + og * 2;  // even; pair (ot0, ot0+1) same segment
    f32x4 acc[8][2];  // [nt 0..7 = all 128 rows][oi]
#pragma unroll
    for (int nt = 0; nt < 8; ++nt)
#pragma unroll
      for (int oi = 0; oi < 2; ++oi) acc[nt][oi] = fz;

#pragma unroll
    for (int kc = 0; kc < 8; ++kc) {
      bf16x8 afr[8], bfr[2];
#pragma unroll
      for (int nt = 0; nt < 8; ++nt) {
        int nn = nt * 16 + l15;
        int wb = (kc * 64 + l4 * 16) ^ ((nn & 7) << 4);
        afr[nt] = *(const bf16x8*)((const char*)Xl + nn * 512 + wb);
      }
#pragma unroll
      for (int oi = 0; oi < 2; ++oi)
        bfr[oi] = *(const bf16x8*)(Wf + ((((ot0 + oi) * 8) + kc) * 64 + lane) * 8);
#pragma unroll
      for (int nt = 0; nt < 8; ++nt)
#pragma unroll
        for (int oi = 0; oi < 2; ++oi)
          acc[nt][oi] = MFMA16(afr[nt], bfr[oi], acc[nt][oi]);
    }

    // ---- epilogue ----
    const int seg = ot0 >> 4;        // 0=q 1=k 2=v
    const int h = (ot0 >> 1) & 7;
    const int base = (b * 8 + h) * 8192;
    if (seg < 2) {
      bf16* dstbuf = (seg == 0) ? q : kk;
      const float scale = (seg == 0) ? 0.17677669529663687f : 1.0f;
      float bias0 = qb[seg * 256 + h * 32 + l15];
      float bias1 = qb[seg * 256 + h * 32 + 16 + l15];
#pragma unroll
      for (int nt = 0; nt < 8; ++nt) {
        // 16 rows x 32 d tile into [16][36] bounce (2-way-free banks)
#pragma unroll
        for (int r = 0; r < 4; ++r) {
          int row = l4 * 4 + r;
          lb[row * 36 + l15] = (bf16)((acc[nt][0][r] + bias0) * scale);
          lb[row * 36 + 16 + l15] = (bf16)((acc[nt][1][r] + bias1) * scale);
        }
        asm volatile("s_waitcnt lgkmcnt(0)" ::: "memory");
        __builtin_amdgcn_sched_barrier(0);
        int row = lane >> 2, ch = lane & 3;
        bf16x8 tv = *(const bf16x8*)(lb + row * 36 + ch * 8);
        asm volatile("s_waitcnt lgkmcnt(0)" ::: "memory");
        __builtin_amdgcn_sched_barrier(0);
        *(bf16x8*)(dstbuf + base + (n0w + nt * 16 + row) * 32 + ch * 8) = tv;
      }
    } else {
      // v: transpose 16d x 32n tiles through LDS -> vT[d][n] 64B rows
#pragma unroll
      for (int oi = 0; oi < 2; ++oi) {
        int ot = ot0 + oi;
        float bias = qb[ot * 16 + l15];
#pragma unroll
        for (int pr = 0; pr < 4; ++pr) {
          f32x4 a0 = acc[2 * pr][oi], a1 = acc[2 * pr + 1][oi];
          int n0p = n0w + pr * 32;
#pragma unroll
          for (int nt = 0; nt < 2; ++nt) {
            f32x4 a = nt ? a1 : a0;
            *(u32*)(lb + l15 * 36 + nt * 16 + l4 * 4) =
                pack2(a[0] + bias, a[1] + bias);
            *(u32*)(lb + l15 * 36 + nt * 16 + l4 * 4 + 2) =
                pack2(a[2] + bias, a[3] + bias);
          }
          asm volatile("s_waitcnt lgkmcnt(0)" ::: "memory");
          __builtin_amdgcn_sched_barrier(0);
          int dl = lane >> 2, chv = lane & 3;
          bf16x4 rv0 = *(bf16x4*)(lb + dl * 36 + chv * 8);
          bf16x4 rv1 = *(bf16x4*)(lb + dl * 36 + chv * 8 + 4);
          asm volatile("s_waitcnt lgkmcnt(0)" ::: "memory");
          __builtin_amdgcn_sched_barrier(0);
          int d2 = (ot & 1) * 16 + dl;
          bf16* dv2 = vT + base + d2 * 256 + n0p + chv * 8;
          *(bf16x4*)dv2 = rv0;
          *(bf16x4*)(dv2 + 4) = rv1;
        }
      }
    }
  }
}

// ---------------- attention per (b, h): fused QK->exp->PV per kt2 ----------------
__global__ __launch_bounds__(256, 4) void k_attn(
    const bf16* __restrict__ q, const bf16* __restrict__ kk,
    const bf16* __restrict__ vT, const bf16* __restrict__ Bsw,
    bf16* __restrict__ ao) {
  __shared__ bf16 Kl[256 * 36];    // 18,432 B
  __shared__ bf16 Ob[4][32 * 36];  // 9,216 B: per-wave output transpose bounce
  const int bh = blockIdx.x;
  const int b = bh >> 3, h = bh & 7;
  const int tid = threadIdx.x;
  const int lane = tid & 63, wave = tid >> 6;
  const int l31 = lane & 31, hi = lane >> 5;

  const bf16* Kg = kk + bh * 8192;
#pragma unroll
  for (int i = 0; i < 4; ++i) {
    int t = tid + i * 256;
    int n = t >> 2, dc = t & 3;
    *(bf16x8*)(Kl + n * 36 + dc * 8) = *(const bf16x8*)(Kg + n * 32 + dc * 8);
  }
  __syncthreads();

  const bf16* Vg = vT + bh * 8192;
  bf16* ob = Ob[wave];
  for (int qi = 0; qi < 2; ++qi) {
    const int qt = wave * 2 + qi, q0 = qt * 32;
    bf16x8 qf0 = *(const bf16x8*)(q + bh * 8192 + (q0 + l31) * 32 + hi * 8);
    bf16x8 qf1 = *(const bf16x8*)(q + bh * 8192 + (q0 + l31) * 32 + 16 + hi * 8);
    const bf16* bq = Bsw + (h * 8 + qt) * 8192 + lane * 16;
    float lsum = 0.f;
    f32x16 o;
#pragma unroll
    for (int i = 0; i < 16; ++i) o[i] = 0.f;
#pragma unroll
    for (int kt2 = 0; kt2 < 8; ++kt2) {
      u32x4 w0 = *(const u32x4*)(bq + kt2 * 1024);       // bias regs 0..7
      u32x4 w1 = *(const u32x4*)(bq + kt2 * 1024 + 8);   // bias regs 8..15
      f32x16 acc;
#pragma unroll
      for (int j = 0; j < 4; ++j) {
        acc[2 * j] = __builtin_bit_cast(float, w0[j] << 16);
        acc[2 * j + 1] = __builtin_bit_cast(float, w0[j] & 0xffff0000u);
        acc[8 + 2 * j] = __builtin_bit_cast(float, w1[j] << 16);
        acc[8 + 2 * j + 1] = __builtin_bit_cast(float, w1[j] & 0xffff0000u);
      }
      bf16x8 kf0 = *(const bf16x8*)(Kl + (kt2 * 32 + l31) * 36 + hi * 8);
      bf16x8 kf1 = *(const bf16x8*)(Kl + (kt2 * 32 + l31) * 36 + 16 + hi * 8);
      acc = MFMA32(kf0, qf0, acc);
      acc = MFMA32(kf1, qf1, acc);
      // exp (no max-shift) + pack; P for this kt2 feeds PV immediately
      u32 lo[4], hw[4];
#pragma unroll
      for (int qq = 0; qq < 4; ++qq) {
        float e0 = __expf(acc[4 * qq]);
        float e1 = __expf(acc[4 * qq + 1]);
        float e2 = __expf(acc[4 * qq + 2]);
        float e3 = __expf(acc[4 * qq + 3]);
        lsum += (e0 + e1) + (e2 + e3);
        lo[qq] = pack2(e0, e1);
        hw[qq] = pack2(e2, e3);
      }
#pragma unroll
      for (int sb = 0; sb < 2; ++sb) {
        u32 keep_lo = hi ? lo[2 * sb + 1] : lo[2 * sb];
        u32 keep_hi = hi ? hw[2 * sb + 1] : hw[2 * sb];
        u32 send_lo = hi ? lo[2 * sb] : lo[2 * sb + 1];
        u32 send_hi = hi ? hw[2 * sb] : hw[2 * sb + 1];
        u32 rlo = __shfl_xor(send_lo, 32);
        u32 rhi = __shfl_xor(send_hi, 32);
        u32x4 bw;
        bw[0] = hi ? rlo : keep_lo;
        bw[1] = hi ? rhi : keep_hi;
        bw[2] = hi ? keep_lo : rlo;
        bw[3] = hi ? keep_hi : rhi;
        bf16x8 pf = __builtin_bit_cast(bf16x8, bw);
        bf16x8 vf = *(const bf16x8*)(Vg + l31 * 256 + kt2 * 32 + sb * 16 + hi * 8);
        o = MFMA32(vf, pf, o);
      }
    }
    lsum += __shfl_xor(lsum, 32);
    const float inv = 1.f / lsum;
    // normalize, transpose via per-wave LDS, store
#pragma unroll
    for (int qq = 0; qq < 4; ++qq) {
      *(u32*)(ob + l31 * 36 + 8 * qq + 4 * hi) =
          pack2(o[4 * qq] * inv, o[4 * qq + 1] * inv);
      *(u32*)(ob + l31 * 36 + 8 * qq + 4 * hi + 2) =
          pack2(o[4 * qq + 2] * inv, o[4 * qq + 3] * inv);
    }
    asm volatile("s_waitcnt lgkmcnt(0)" ::: "memory");
    __builtin_amdgcn_sched_barrier(0);
    int n2 = lane >> 1, ch = lane & 1;
    bf16x4 r0 = *(bf16x4*)(ob + n2 * 36 + ch * 16);
    bf16x4 r1 = *(bf16x4*)(ob + n2 * 36 + ch * 16 + 4);
    bf16x4 r2 = *(bf16x4*)(ob + n2 * 36 + ch * 16 + 8);
    bf16x4 r3 = *(bf16x4*)(ob + n2 * 36 + ch * 16 + 12);
    asm volatile("s_waitcnt lgkmcnt(0)" ::: "memory");
    __builtin_amdgcn_sched_barrier(0);
    bf16* dst = ao + (b * 256 + q0 + n2) * 256 + h * 32 + ch * 16;
    *(bf16x4*)dst = r0;
    *(bf16x4*)(dst + 4) = r1;
    *(bf16x4*)(dst + 8) = r2;
    *(bf16x4*)(dst + 12) = r3;
  }
}

// ---------------- output projection: block=(b, out-half), LDS-staged ao ----------------
__global__ __launch_bounds__(512) void k_proj(
    const bf16* __restrict__ ao, const bf16* __restrict__ Wp,
    const float* __restrict__ pb, float* __restrict__ out) {
  __shared__ bf16 Sl[2][16 * 264];  // 2 x 8,448 B
  const int b = blockIdx.x & 255;
  const int oh = blockIdx.x >> 8;
  const int tid = threadIdx.x;
  const int lane = tid & 63, wave = tid >> 6;
  const int l15 = lane & 15, l4 = lane >> 4;
  const int ot = oh * 8 + wave;
  bf16x8 af[8];
  const bf16* wr = Wp + (ot * 16 + l15) * 256 + l4 * 8;
#pragma unroll
  for (int kc = 0; kc < 8; ++kc) af[kc] = *(const bf16x8*)(wr + kc * 32);
  float bias[4];
#pragma unroll
  for (int r = 0; r < 4; ++r) bias[r] = pb[ot * 16 + l4 * 4 + r];
  const bf16* aob = ao + b * 65536;
  float* outb = out + b * 65536 + ot * 16 * 256;
  const int sr = tid >> 5, sc = (tid & 31) * 8;

  *(bf16x8*)(Sl[0] + sr * 264 + sc) = *(const bf16x8*)(aob + sr * 256 + sc);
  __syncthreads();

  const f32x4 fz = {0.f, 0.f, 0.f, 0.f};
  for (int nt = 0; nt < 16; ++nt) {
    const int cur = nt & 1;
    if (nt < 15)
      *(bf16x8*)(Sl[cur ^ 1] + sr * 264 + sc) =
          *(const bf16x8*)(aob + ((nt + 1) * 16 + sr) * 256 + sc);
    f32x4 acc = fz;
#pragma unroll
    for (int kc = 0; kc < 8; ++kc) {
      bf16x8 bfr = *(const bf16x8*)(Sl[cur] + l15 * 264 + kc * 32 + l4 * 8);
      acc = MFMA16(af[kc], bfr, acc);
    }
#pragma unroll
    for (int r = 0; r < 4; ++r)
      outb[(l4 * 4 + r) * 256 + nt * 16 + l15] = acc[r] + bias[r];
    __syncthreads();
  }
}

extern "C" void kernel_launch(void* const* d_in, const int* in_sizes, int n_in,
                              void* d_out, int out_size, void* d_ws, size_t ws_size,
                              hipStream_t stream) {
  const float* x    = (const float*)d_in[0];
  const float* qkvw = (const float*)d_in[1];
  const float* qkvb = (const float*)d_in[2];
  const float* pjw  = (const float*)d_in[3];
  const float* pjb  = (const float*)d_in[4];
  const float* ppw  = (const float*)d_in[5];
  const float* ppb  = (const float*)d_in[6];
  const float* g1 = (const float*)d_in[7];   const float* b1 = (const float*)d_in[8];
  const float* f1w = (const float*)d_in[9];  const float* f1b = (const float*)d_in[10];
  const float* g2 = (const float*)d_in[11];  const float* b2 = (const float*)d_in[12];
  const float* f2w = (const float*)d_in[13]; const float* f2b = (const float*)d_in[14];
  const float* g3 = (const float*)d_in[15];  const float* b3 = (const float*)d_in[16];
  const float* f3w = (const float*)d_in[17]; const float* f3b = (const float*)d_in[18];
  float* out = (float*)d_out;

  // ws: q | k | vT | ao (16,777,216 bf16 each) | ptab 8192 f32 | Wf 196608 bf16
  //     | Wproj 65536 bf16 | Bsw 524288 bf16
  bf16* wsq  = (bf16*)d_ws;
  bf16* wsk  = wsq + 16777216;
  bf16* wsv  = wsk + 16777216;
  bf16* wsao = wsv + 16777216;
  float* ptab = (float*)(wsao + 16777216);
  bf16* wqkv = (bf16*)(ptab + 8192);
  bf16* wpj  = wqkv + 196608;
  bf16* bsw  = wpj + 65536;

  hipLaunchKernelGGL(k_prep, dim3(164), dim3(256), 0, stream, qkvw, wqkv, pjw,
                     wpj, ppw, ppb, g1, b1, f1w, f1b, g2, b2, f2w, f2b, g3, b3,
                     f3w, f3b, ptab);
  hipLaunchKernelGGL(k_bias, dim3(128), dim3(256), 0, stream, ptab, bsw);
  hipLaunchKernelGGL(k_qkv, dim3(512), dim3(512), 0, stream, x, wqkv, qkvb, wsq,
                     wsk, wsv);
  hipLaunchKernelGGL(k_attn, dim3(2048), dim3(256), 0, stream, wsq, wsk, wsv,
                     bsw, wsao);
  hipLaunchKernelGGL(k_proj, dim3(512), dim3(512), 0, stream, wsao, wpj, pjb, out);
}

// Round 22
// 146.542 us; speedup vs baseline: 1.1235x; 1.0656x over previous
//
#include <hip/hip_runtime.h>

typedef __bf16 bf16;
typedef __bf16 bf16x8 __attribute__((ext_vector_type(8)));
typedef __bf16 bf16x4 __attribute__((ext_vector_type(4)));
typedef float f32x4 __attribute__((ext_vector_type(4)));
typedef float f32x16 __attribute__((ext_vector_type(16)));
typedef unsigned int u32;
typedef unsigned int u32x2 __attribute__((ext_vector_type(2)));
typedef unsigned int u32x4 __attribute__((ext_vector_type(4)));

#define MFMA16(a, b, c) __builtin_amdgcn_mfma_f32_16x16x32_bf16(a, b, c, 0, 0, 0)
#define MFMA32(a, b, c) __builtin_amdgcn_mfma_f32_32x32x16_bf16(a, b, c, 0, 0, 0)

__device__ __forceinline__ u32 pack2(float a, float b) {
  unsigned short ua = __builtin_bit_cast(unsigned short, (bf16)a);
  unsigned short ub = __builtin_bit_cast(unsigned short, (bf16)b);
  return (u32)ua | ((u32)ub << 16);
}

__device__ __forceinline__ void lnrelu16(const float* in, float* out,
                                         const float* __restrict__ g,
                                         const float* __restrict__ b) {
  float mu = 0.f;
#pragma unroll
  for (int t = 0; t < 16; ++t) mu += in[t];
  mu *= 0.0625f;
  float var = 0.f;
#pragma unroll
  for (int t = 0; t < 16; ++t) { float d = in[t] - mu; var += d * d; }
  var *= 0.0625f;
  float inv = rsqrtf(var + 1e-5f);
#pragma unroll
  for (int t = 0; t < 16; ++t) {
    float v = (in[t] - mu) * inv * g[t] + b[t];
    out[t] = fmaxf(v, 0.f);
  }
}

// ---------------- merged prep: wpack (blk 0-95) | proj cvt (96-159) | dpb (160-163) ----------------
__global__ __launch_bounds__(256) void k_prep(
    const float* __restrict__ qkvw, bf16* __restrict__ wqkv,
    const float* __restrict__ pjw, bf16* __restrict__ wpj,
    const float* __restrict__ ppw, const float* __restrict__ ppb,
    const float* __restrict__ g1, const float* __restrict__ b1,
    const float* __restrict__ f1w, const float* __restrict__ f1b,
    const float* __restrict__ g2, const float* __restrict__ b2,
    const float* __restrict__ f2w, const float* __restrict__ f2b,
    const float* __restrict__ g3, const float* __restrict__ b3,
    const float* __restrict__ f3w, const float* __restrict__ f3b,
    float* __restrict__ ptab) {
  const int blk = blockIdx.x;
  if (blk < 96) {
    // qkv_w -> B-fragment-major pack: Wf[(ot*8+kc)*64+lane][8]
    int t = blk * 256 + threadIdx.x;
    int lane = t & 63, fk = t >> 6;
    int ot = fk >> 3, kc = fk & 7;
    int o = ot * 16 + (lane & 15), cb = kc * 32 + (lane >> 4) * 8;
    const float* src = qkvw + o * 256 + cb;
    bf16x8 v;
#pragma unroll
    for (int j = 0; j < 8; ++j) v[j] = (bf16)src[j];
    *(bf16x8*)(wqkv + (size_t)t * 8) = v;
  } else if (blk < 160) {
    // proj_w fp32 -> bf16
    int i = (blk - 96) * 256 + threadIdx.x;
    if (i < 16384) {
      float4 v = ((const float4*)pjw)[i];
      bf16x4 o;
      o[0] = (bf16)v.x; o[1] = (bf16)v.y; o[2] = (bf16)v.z; o[3] = (bf16)v.w;
      ((bf16x4*)wpj)[i] = o;
    }
  } else {
    // dynamic position-bias MLP (961 rows)
    int l = (blk - 160) * 256 + threadIdx.x;
    if (l >= 961) return;
    float dh = (float)(l / 31) - 15.f;
    float dw = (float)(l % 31) - 15.f;
    float p[16], a[16], y[16];
#pragma unroll
    for (int t = 0; t < 16; ++t)
      p[t] = dh * ppw[2 * t] + dw * ppw[2 * t + 1] + ppb[t];
    lnrelu16(p, a, g1, b1);
#pragma unroll
    for (int t = 0; t < 16; ++t) {
      float s = f1b[t];
#pragma unroll
      for (int u = 0; u < 16; ++u) s += a[u] * f1w[t * 16 + u];
      y[t] = s;
    }
    lnrelu16(y, a, g2, b2);
#pragma unroll
    for (int t = 0; t < 16; ++t) {
      float s = f2b[t];
#pragma unroll
      for (int u = 0; u < 16; ++u) s += a[u] * f2w[t * 16 + u];
      p[t] = s;
    }
    lnrelu16(p, a, g3, b3);
#pragma unroll
    for (int t = 0; t < 8; ++t) {
      float s = f3b[t];
#pragma unroll
      for (int u = 0; u < 16; ++u) s += a[u] * f3w[t * 16 + u];
      ptab[l * 8 + t] = s;
    }
  }
}

// ---------------- bias table (bf16) in 32x32 MFMA D-fragment order ----------------
__global__ __launch_bounds__(256) void k_bias(const float* __restrict__ ptab,
                                              bf16* __restrict__ Bsw) {
  int idx = blockIdx.x * 256 + threadIdx.x;  // 128 blocks -> 32768 threads
  int lane = idx & 63, tg = idx >> 6;        // tg 0..511
  int h = tg >> 6, qt = (tg >> 3) & 7, kt2 = tg & 7;
  int l31 = lane & 31, hi2 = lane >> 5;
  int n = qt * 32 + l31;
  int i1 = n >> 4, j1 = n & 15;
  bf16x8 o0, o1;
#pragma unroll
  for (int reg = 0; reg < 16; ++reg) {
    int key = kt2 * 32 + (reg & 3) + 8 * (reg >> 2) + 4 * hi2;
    int i2 = key >> 4, j2 = key & 15;
    int li = (i1 - i2 + 15) * 31 + (j1 - j2 + 15);
    bf16 v = (bf16)ptab[li * 8 + h];
    if (reg < 8) o0[reg] = v; else o1[reg - 8] = v;
  }
  bf16* dst = Bsw + tg * 1024 + lane * 16;
  *(bf16x8*)dst = o0;
  *(bf16x8*)(dst + 8) = o1;
}

// ---------------- qkv GEMM: (B*N,256) x (768,256)^T ----------------
// 64 rows/block (grid 1024, 512 threads): Xl 32KB -> 3 blocks/CU (24
// waves/CU, was 16) for HBM BW utilization; R21's no-duplication wave
// decomposition kept (8 waves x 6 distinct ot x all 64 rows).
__global__ __launch_bounds__(512) void k_qkv(
    const float* __restrict__ x, const bf16* __restrict__ Wf,
    const float* __restrict__ qb, bf16* __restrict__ q, bf16* __restrict__ kk,
    bf16* __restrict__ vT) {
  __shared__ bf16 Xl[64 * 256];    // 32,768 B, swizzled [n][c]
  __shared__ bf16 Vb[8][16 * 36];  // 9,216 B: per-wave bounce (v AND q/k)
  const int b = blockIdx.x >> 2;
  const int nq = blockIdx.x & 3;
  const int tid = threadIdx.x;
  const int lane = tid & 63;
  const int wave = tid >> 6;
  const int l15 = lane & 15, l4 = lane >> 4;
  const int n0w = nq * 64;

  // ---- stage x[b][c][n0w+n] -> Xl[n][c]: issue-early loads, quad
  //      transpose + swizzled writes (64 rows x 256 c) ----
  {
    const float* xb = x + b * 65536 + n0w;
    const int p = tid & 3;
    const int Q = tid >> 2;       // 0..127
    const int n0 = (Q & 15) * 4;  // 0..60
    const int cg = Q >> 4;        // 0..7
    float4 vv[8];
#pragma unroll
    for (int it = 0; it < 8; ++it) {
      const int c0 = (cg + it * 8) * 4;
      vv[it] = *(const float4*)(xb + (c0 + p) * 256 + n0);
    }
#pragma unroll
    for (int it = 0; it < 8; ++it) {
      const int c0 = (cg + it * 8) * 4;
      float4 v = vv[it];
      u32 u0 = pack2(v.x, v.y);
      u32 u1 = pack2(v.z, v.w);
      u32 su0 = __shfl_xor(u0, 1);
      u32 su1 = __shfl_xor(u1, 1);
      u32 w, z;
      if (p & 1) {
        w = (su0 >> 16) | (u0 & 0xffff0000u);
        z = (su1 >> 16) | (u1 & 0xffff0000u);
      } else {
        w = (u0 & 0xffffu) | (su0 << 16);
        z = (u1 & 0xffffu) | (su1 << 16);
      }
      u32 sw = __shfl_xor(w, 2);
      u32 sz = __shfl_xor(z, 2);
      u32x2 o2;
      o2[0] = (p & 2) ? sz : w;
      o2[1] = (p & 2) ? z : sw;
      const int n = n0 + p;
      const int wb = (2 * c0) ^ ((n & 7) << 4);
      *(u32x2*)((char*)Xl + n * 512 + wb) = o2;
    }
  }
  __syncthreads();

  const f32x4 fz = {0.f, 0.f, 0.f, 0.f};
  bf16* lb = Vb[wave];
  for (int og = 0; og < 3; ++og) {
    const int ot0 = wave * 6 + og * 2;  // even; pair (ot0, ot0+1) same segment
    f32x4 acc[4][2];  // [nt 0..3 = all 64 rows][oi]
#pragma unroll
    for (int nt = 0; nt < 4; ++nt)
#pragma unroll
      for (int oi = 0; oi < 2; ++oi) acc[nt][oi] = fz;

#pragma unroll
    for (int kc = 0; kc < 8; ++kc) {
      bf16x8 afr[4], bfr[2];
#pragma unroll
      for (int nt = 0; nt < 4; ++nt) {
        int nn = nt * 16 + l15;
        int wb = (kc * 64 + l4 * 16) ^ ((nn & 7) << 4);
        afr[nt] = *(const bf16x8*)((const char*)Xl + nn * 512 + wb);
      }
#pragma unroll
      for (int oi = 0; oi < 2; ++oi)
        bfr[oi] = *(const bf16x8*)(Wf + ((((ot0 + oi) * 8) + kc) * 64 + lane) * 8);
#pragma unroll
      for (int nt = 0; nt < 4; ++nt)
#pragma unroll
        for (int oi = 0; oi < 2; ++oi)
          acc[nt][oi] = MFMA16(afr[nt], bfr[oi], acc[nt][oi]);
    }

    // ---- epilogue ----
    const int seg = ot0 >> 4;        // 0=q 1=k 2=v
    const int h = (ot0 >> 1) & 7;
    const int base = (b * 8 + h) * 8192;
    if (seg < 2) {
      bf16* dstbuf = (seg == 0) ? q : kk;
      const float scale = (seg == 0) ? 0.17677669529663687f : 1.0f;
      float bias0 = qb[seg * 256 + h * 32 + l15];
      float bias1 = qb[seg * 256 + h * 32 + 16 + l15];
#pragma unroll
      for (int nt = 0; nt < 4; ++nt) {
        // 16 rows x 32 d tile into [16][36] bounce (2-way-free banks)
#pragma unroll
        for (int r = 0; r < 4; ++r) {
          int row = l4 * 4 + r;
          lb[row * 36 + l15] = (bf16)((acc[nt][0][r] + bias0) * scale);
          lb[row * 36 + 16 + l15] = (bf16)((acc[nt][1][r] + bias1) * scale);
        }
        asm volatile("s_waitcnt lgkmcnt(0)" ::: "memory");
        __builtin_amdgcn_sched_barrier(0);
        int row = lane >> 2, ch = lane & 3;
        bf16x8 tv = *(const bf16x8*)(lb + row * 36 + ch * 8);
        asm volatile("s_waitcnt lgkmcnt(0)" ::: "memory");
        __builtin_amdgcn_sched_barrier(0);
        *(bf16x8*)(dstbuf + base + (n0w + nt * 16 + row) * 32 + ch * 8) = tv;
      }
    } else {
      // v: transpose 16d x 32n tiles through LDS -> vT[d][n] 64B rows
#pragma unroll
      for (int oi = 0; oi < 2; ++oi) {
        int ot = ot0 + oi;
        float bias = qb[ot * 16 + l15];
#pragma unroll
        for (int pr = 0; pr < 2; ++pr) {
          f32x4 a0 = acc[2 * pr][oi], a1 = acc[2 * pr + 1][oi];
          int n0p = n0w + pr * 32;
#pragma unroll
          for (int nt = 0; nt < 2; ++nt) {
            f32x4 a = nt ? a1 : a0;
            *(u32*)(lb + l15 * 36 + nt * 16 + l4 * 4) =
                pack2(a[0] + bias, a[1] + bias);
            *(u32*)(lb + l15 * 36 + nt * 16 + l4 * 4 + 2) =
                pack2(a[2] + bias, a[3] + bias);
          }
          asm volatile("s_waitcnt lgkmcnt(0)" ::: "memory");
          __builtin_amdgcn_sched_barrier(0);
          int dl = lane >> 2, chv = lane & 3;
          bf16x4 rv0 = *(bf16x4*)(lb + dl * 36 + chv * 8);
          bf16x4 rv1 = *(bf16x4*)(lb + dl * 36 + chv * 8 + 4);
          asm volatile("s_waitcnt lgkmcnt(0)" ::: "memory");
          __builtin_amdgcn_sched_barrier(0);
          int d2 = (ot & 1) * 16 + dl;
          bf16* dv2 = vT + base + d2 * 256 + n0p + chv * 8;
          *(bf16x4*)dv2 = rv0;
          *(bf16x4*)(dv2 + 4) = rv1;
        }
      }
    }
  }
}

// ---------------- attention per (b, h): fused QK->exp->PV per kt2 ----------------
__global__ __launch_bounds__(256, 4) void k_attn(
    const bf16* __restrict__ q, const bf16* __restrict__ kk,
    const bf16* __restrict__ vT, const bf16* __restrict__ Bsw,
    bf16* __restrict__ ao) {
  __shared__ bf16 Kl[256 * 36];    // 18,432 B
  __shared__ bf16 Ob[4][32 * 36];  // 9,216 B: per-wave output transpose bounce
  const int bh = blockIdx.x;
  const int b = bh >> 3, h = bh & 7;
  const int tid = threadIdx.x;
  const int lane = tid & 63, wave = tid >> 6;
  const int l31 = lane & 31, hi = lane >> 5;

  const bf16* Kg = kk + bh * 8192;
#pragma unroll
  for (int i = 0; i < 4; ++i) {
    int t = tid + i * 256;
    int n = t >> 2, dc = t & 3;
    *(bf16x8*)(Kl + n * 36 + dc * 8) = *(const bf16x8*)(Kg + n * 32 + dc * 8);
  }
  __syncthreads();

  const bf16* Vg = vT + bh * 8192;
  bf16* ob = Ob[wave];
  for (int qi = 0; qi < 2; ++qi) {
    const int qt = wave * 2 + qi, q0 = qt * 32;
    bf16x8 qf0 = *(const bf16x8*)(q + bh * 8192 + (q0 + l31) * 32 + hi * 8);
    bf16x8 qf1 = *(const bf16x8*)(q + bh * 8192 + (q0 + l31) * 32 + 16 + hi * 8);
    const bf16* bq = Bsw + (h * 8 + qt) * 8192 + lane * 16;
    float lsum = 0.f;
    f32x16 o;
#pragma unroll
    for (int i = 0; i < 16; ++i) o[i] = 0.f;
#pragma unroll
    for (int kt2 = 0; kt2 < 8; ++kt2) {
      u32x4 w0 = *(const u32x4*)(bq + kt2 * 1024);       // bias regs 0..7
      u32x4 w1 = *(const u32x4*)(bq + kt2 * 1024 + 8);   // bias regs 8..15
      f32x16 acc;
#pragma unroll
      for (int j = 0; j < 4; ++j) {
        acc[2 * j] = __builtin_bit_cast(float, w0[j] << 16);
        acc[2 * j + 1] = __builtin_bit_cast(float, w0[j] & 0xffff0000u);
        acc[8 + 2 * j] = __builtin_bit_cast(float, w1[j] << 16);
        acc[8 + 2 * j + 1] = __builtin_bit_cast(float, w1[j] & 0xffff0000u);
      }
      bf16x8 kf0 = *(const bf16x8*)(Kl + (kt2 * 32 + l31) * 36 + hi * 8);
      bf16x8 kf1 = *(const bf16x8*)(Kl + (kt2 * 32 + l31) * 36 + 16 + hi * 8);
      acc = MFMA32(kf0, qf0, acc);
      acc = MFMA32(kf1, qf1, acc);
      // exp (no max-shift) + pack; P for this kt2 feeds PV immediately
      u32 lo[4], hw[4];
#pragma unroll
      for (int qq = 0; qq < 4; ++qq) {
        float e0 = __expf(acc[4 * qq]);
        float e1 = __expf(acc[4 * qq + 1]);
        float e2 = __expf(acc[4 * qq + 2]);
        float e3 = __expf(acc[4 * qq + 3]);
        lsum += (e0 + e1) + (e2 + e3);
        lo[qq] = pack2(e0, e1);
        hw[qq] = pack2(e2, e3);
      }
#pragma unroll
      for (int sb = 0; sb < 2; ++sb) {
        u32 keep_lo = hi ? lo[2 * sb + 1] : lo[2 * sb];
        u32 keep_hi = hi ? hw[2 * sb + 1] : hw[2 * sb];
        u32 send_lo = hi ? lo[2 * sb] : lo[2 * sb + 1];
        u32 send_hi = hi ? hw[2 * sb] : hw[2 * sb + 1];
        u32 rlo = __shfl_xor(send_lo, 32);
        u32 rhi = __shfl_xor(send_hi, 32);
        u32x4 bw;
        bw[0] = hi ? rlo : keep_lo;
        bw[1] = hi ? rhi : keep_hi;
        bw[2] = hi ? keep_lo : rlo;
        bw[3] = hi ? keep_hi : rhi;
        bf16x8 pf = __builtin_bit_cast(bf16x8, bw);
        bf16x8 vf = *(const bf16x8*)(Vg + l31 * 256 + kt2 * 32 + sb * 16 + hi * 8);
        o = MFMA32(vf, pf, o);
      }
    }
    lsum += __shfl_xor(lsum, 32);
    const float inv = 1.f / lsum;
    // normalize, transpose via per-wave LDS, store
#pragma unroll
    for (int qq = 0; qq < 4; ++qq) {
      *(u32*)(ob + l31 * 36 + 8 * qq + 4 * hi) =
          pack2(o[4 * qq] * inv, o[4 * qq + 1] * inv);
      *(u32*)(ob + l31 * 36 + 8 * qq + 4 * hi + 2) =
          pack2(o[4 * qq + 2] * inv, o[4 * qq + 3] * inv);
    }
    asm volatile("s_waitcnt lgkmcnt(0)" ::: "memory");
    __builtin_amdgcn_sched_barrier(0);
    int n2 = lane >> 1, ch = lane & 1;
    bf16x4 r0 = *(bf16x4*)(ob + n2 * 36 + ch * 16);
    bf16x4 r1 = *(bf16x4*)(ob + n2 * 36 + ch * 16 + 4);
    bf16x4 r2 = *(bf16x4*)(ob + n2 * 36 + ch * 16 + 8);
    bf16x4 r3 = *(bf16x4*)(ob + n2 * 36 + ch * 16 + 12);
    asm volatile("s_waitcnt lgkmcnt(0)" ::: "memory");
    __builtin_amdgcn_sched_barrier(0);
    bf16* dst = ao + (b * 256 + q0 + n2) * 256 + h * 32 + ch * 16;
    *(bf16x4*)dst = r0;
    *(bf16x4*)(dst + 4) = r1;
    *(bf16x4*)(dst + 8) = r2;
    *(bf16x4*)(dst + 12) = r3;
  }
}

// ---------------- output projection: block=(b, out-half), LDS-staged ao ----------------
__global__ __launch_bounds__(512) void k_proj(
    const bf16* __restrict__ ao, const bf16* __restrict__ Wp,
    const float* __restrict__ pb, float* __restrict__ out) {
  __shared__ bf16 Sl[2][16 * 264];  // 2 x 8,448 B
  const int b = blockIdx.x & 255;
  const int oh = blockIdx.x >> 8;
  const int tid = threadIdx.x;
  const int lane = tid & 63, wave = tid >> 6;
  const int l15 = lane & 15, l4 = lane >> 4;
  const int ot = oh * 8 + wave;
  bf16x8 af[8];
  const bf16* wr = Wp + (ot * 16 + l15) * 256 + l4 * 8;
#pragma unroll
  for (int kc = 0; kc < 8; ++kc) af[kc] = *(const bf16x8*)(wr + kc * 32);
  float bias[4];
#pragma unroll
  for (int r = 0; r < 4; ++r) bias[r] = pb[ot * 16 + l4 * 4 + r];
  const bf16* aob = ao + b * 65536;
  float* outb = out + b * 65536 + ot * 16 * 256;
  const int sr = tid >> 5, sc = (tid & 31) * 8;

  *(bf16x8*)(Sl[0] + sr * 264 + sc) = *(const bf16x8*)(aob + sr * 256 + sc);
  __syncthreads();

  const f32x4 fz = {0.f, 0.f, 0.f, 0.f};
  for (int nt = 0; nt < 16; ++nt) {
    const int cur = nt & 1;
    if (nt < 15)
      *(bf16x8*)(Sl[cur ^ 1] + sr * 264 + sc) =
          *(const bf16x8*)(aob + ((nt + 1) * 16 + sr) * 256 + sc);
    f32x4 acc = fz;
#pragma unroll
    for (int kc = 0; kc < 8; ++kc) {
      bf16x8 bfr = *(const bf16x8*)(Sl[cur] + l15 * 264 + kc * 32 + l4 * 8);
      acc = MFMA16(af[kc], bfr, acc);
    }
#pragma unroll
    for (int r = 0; r < 4; ++r)
      outb[(l4 * 4 + r) * 256 + nt * 16 + l15] = acc[r] + bias[r];
    __syncthreads();
  }
}

extern "C" void kernel_launch(void* const* d_in, const int* in_sizes, int n_in,
                              void* d_out, int out_size, void* d_ws, size_t ws_size,
                              hipStream_t stream) {
  const float* x    = (const float*)d_in[0];
  const float* qkvw = (const float*)d_in[1];
  const float* qkvb = (const float*)d_in[2];
  const float* pjw  = (const float*)d_in[3];
  const float* pjb  = (const float*)d_in[4];
  const float* ppw  = (const float*)d_in[5];
  const float* ppb  = (const float*)d_in[6];
  const float* g1 = (const float*)d_in[7];   const float* b1 = (const float*)d_in[8];
  const float* f1w = (const float*)d_in[9];  const float* f1b = (const float*)d_in[10];
  const float* g2 = (const float*)d_in[11];  const float* b2 = (const float*)d_in[12];
  const float* f2w = (const float*)d_in[13]; const float* f2b = (const float*)d_in[14];
  const float* g3 = (const float*)d_in[15];  const float* b3 = (const float*)d_in[16];
  const float* f3w = (const float*)d_in[17]; const float* f3b = (const float*)d_in[18];
  float* out = (float*)d_out;

  // ws: q | k | vT | ao (16,777,216 bf16 each) | ptab 8192 f32 | Wf 196608 bf16
  //     | Wproj 65536 bf16 | Bsw 524288 bf16
  bf16* wsq  = (bf16*)d_ws;
  bf16* wsk  = wsq + 16777216;
  bf16* wsv  = wsk + 16777216;
  bf16* wsao = wsv + 16777216;
  float* ptab = (float*)(wsao + 16777216);
  bf16* wqkv = (bf16*)(ptab + 8192);
  bf16* wpj  = wqkv + 196608;
  bf16* bsw  = wpj + 65536;

  hipLaunchKernelGGL(k_prep, dim3(164), dim3(256), 0, stream, qkvw, wqkv, pjw,
                     wpj, ppw, ppb, g1, b1, f1w, f1b, g2, b2, f2w, f2b, g3, b3,
                     f3w, f3b, ptab);
  hipLaunchKernelGGL(k_bias, dim3(128), dim3(256), 0, stream, ptab, bsw);
  hipLaunchKernelGGL(k_qkv, dim3(1024), dim3(512), 0, stream, x, wqkv, qkvb,
                     wsq, wsk, wsv);
  hipLaunchKernelGGL(k_attn, dim3(2048), dim3(256), 0, stream, wsq, wsk, wsv,
                     bsw, wsao);
  hipLaunchKernelGGL(k_proj, dim3(512), dim3(512), 0, stream, wsao, wpj, pjb, out);
}